// Round 1
// baseline (998.497 us; speedup 1.0000x reference)
//
#include <hip/hip_runtime.h>

// GCN VGAE encoder:
//   h  = relu((A @ x) @ W1 + b1)          [associativity: A(xW) == (Ax)W]
//   mu = (A @ h) @ Wmu + bmu ; lv = (A @ h) @ Wlv + blv
// A = D^-1/2 (Adj + I) D^-1/2 with deg on dst side.
// Strategy: build CSR by dst each call (counts -> scan -> fill), then
// pull-mode aggregation, one wave per node, lane = feature dim; dense 64x64
// GEMM fused into the aggregation epilogue with weight columns in VGPRs.

__global__ __launch_bounds__(256) void count_edges(const int* __restrict__ dst,
                                                   int* __restrict__ counts, int E) {
  int e = blockIdx.x * blockDim.x + threadIdx.x;
  if (e < E) atomicAdd(&counts[dst[e]], 1);
}

// Single-block exclusive scan over N counts; also writes dinv and cursor init.
__global__ __launch_bounds__(1024) void scan_deg(const int* __restrict__ counts,
                                                 int* __restrict__ row_ptr,
                                                 int* __restrict__ cursor,
                                                 float* __restrict__ dinv, int n) {
  __shared__ int sums[1024];
  int t = threadIdx.x;
  int chunk = (n + 1023) >> 10;
  int lo = t * chunk;
  int hi = lo + chunk;
  if (lo > n) lo = n;
  if (hi > n) hi = n;
  int s = 0;
  for (int i = lo; i < hi; ++i) {
    int c = counts[i];
    s += c;
    dinv[i] = rsqrtf(1.0f + (float)c);  // deg includes self-loop
  }
  sums[t] = s;
  __syncthreads();
  // Hillis-Steele inclusive scan over 1024 partials
  for (int off = 1; off < 1024; off <<= 1) {
    int v = (t >= off) ? sums[t - off] : 0;
    __syncthreads();
    sums[t] += v;
    __syncthreads();
  }
  int run = (t == 0) ? 0 : sums[t - 1];
  for (int i = lo; i < hi; ++i) {
    row_ptr[i] = run;
    cursor[i] = run;
    run += counts[i];
  }
  if (t == 1023) row_ptr[n] = sums[1023];
}

__global__ __launch_bounds__(256) void fill_csr(const int* __restrict__ src,
                                                const int* __restrict__ dst,
                                                const float* __restrict__ dinv,
                                                int* __restrict__ cursor,
                                                int2* __restrict__ pairs, int E) {
  int e = blockIdx.x * blockDim.x + threadIdx.x;
  if (e < E) {
    int s = src[e];
    int d = dst[e];
    int pos = atomicAdd(&cursor[d], 1);
    pairs[pos] = make_int2(s, __float_as_int(dinv[s]));
  }
}

// Layer 1: y = A @ x (pull), then h = relu(y @ W1 + b1). One wave per row.
__global__ __launch_bounds__(256) void agg_layer1(const float* __restrict__ x,
                                                  const int2* __restrict__ pairs,
                                                  const int* __restrict__ row_ptr,
                                                  const float* __restrict__ W1,
                                                  const float* __restrict__ b1,
                                                  float* __restrict__ h, int n) {
  const int lane = threadIdx.x & 63;
  float w[64];
#pragma unroll
  for (int k = 0; k < 64; ++k) w[k] = W1[k * 64 + lane];  // column `lane` of W1
  const float bias = b1[lane];

  int wid = blockIdx.x * (blockDim.x >> 6) + (threadIdx.x >> 6);
  int nw = gridDim.x * (blockDim.x >> 6);
  for (int i = wid; i < n; i += nw) {
    int start = row_ptr[i];
    int end = row_ptr[i + 1];
    float acc = 0.f;
    for (int base = start; base < end; base += 64) {
      int m = end - base;
      if (m > 64) m = 64;
      int2 p = make_int2(0, 0);
      if (lane < m) p = pairs[base + lane];
      for (int e = 0; e < m; ++e) {
        int idx = __shfl(p.x, e);
        float ws = __int_as_float(__shfl(p.y, e));
        acc += ws * x[(size_t)idx * 64 + lane];  // coalesced 256B row gather
      }
    }
    float di = rsqrtf((float)(1 + end - start));
    float y = di * acc + di * di * x[(size_t)i * 64 + lane];
    // dense epilogue: out[lane] = sum_k y[k] * W1[k][lane] + b1[lane]
    float out = bias;
#pragma unroll
    for (int k = 0; k < 64; ++k) out += __shfl(y, k) * w[k];
    h[(size_t)i * 64 + lane] = fmaxf(out, 0.f);
  }
}

// Layer 2: y = A @ h, then mu = y@Wmu + bmu (lanes 0-31), lv = y@Wlv + blv (32-63).
__global__ __launch_bounds__(256) void agg_layer2(const float* __restrict__ hin,
                                                  const int2* __restrict__ pairs,
                                                  const int* __restrict__ row_ptr,
                                                  const float* __restrict__ Wmu,
                                                  const float* __restrict__ bmu,
                                                  const float* __restrict__ Wlv,
                                                  const float* __restrict__ blv,
                                                  float* __restrict__ out_mu,
                                                  float* __restrict__ out_lv, int n) {
  const int lane = threadIdx.x & 63;
  const int col = lane & 31;
  const float* Wsel = (lane < 32) ? Wmu : Wlv;
  float w[64];
#pragma unroll
  for (int k = 0; k < 64; ++k) w[k] = Wsel[k * 32 + col];
  const float bias = (lane < 32) ? bmu[col] : blv[col];

  int wid = blockIdx.x * (blockDim.x >> 6) + (threadIdx.x >> 6);
  int nw = gridDim.x * (blockDim.x >> 6);
  for (int i = wid; i < n; i += nw) {
    int start = row_ptr[i];
    int end = row_ptr[i + 1];
    float acc = 0.f;
    for (int base = start; base < end; base += 64) {
      int m = end - base;
      if (m > 64) m = 64;
      int2 p = make_int2(0, 0);
      if (lane < m) p = pairs[base + lane];
      for (int e = 0; e < m; ++e) {
        int idx = __shfl(p.x, e);
        float ws = __int_as_float(__shfl(p.y, e));
        acc += ws * hin[(size_t)idx * 64 + lane];
      }
    }
    float di = rsqrtf((float)(1 + end - start));
    float y = di * acc + di * di * hin[(size_t)i * 64 + lane];
    float out = bias;
#pragma unroll
    for (int k = 0; k < 64; ++k) out += __shfl(y, k) * w[k];
    if (lane < 32)
      out_mu[(size_t)i * 32 + col] = out;
    else
      out_lv[(size_t)i * 32 + col] = out;
  }
}

extern "C" void kernel_launch(void* const* d_in, const int* in_sizes, int n_in,
                              void* d_out, int out_size, void* d_ws, size_t ws_size,
                              hipStream_t stream) {
  const float* x = (const float*)d_in[0];
  const int* ei = (const int*)d_in[1];  // [2, E] row-major int32
  const float* W1 = (const float*)d_in[2];
  const float* b1 = (const float*)d_in[3];
  const float* Wmu = (const float*)d_in[4];
  const float* bmu = (const float*)d_in[5];
  const float* Wlv = (const float*)d_in[6];
  const float* blv = (const float*)d_in[7];

  const int N = in_sizes[0] / 64;
  const int E = in_sizes[1] / 2;
  const int* src = ei;
  const int* dst = ei + E;

  auto align256 = [](size_t v) { return (v + 255) & ~(size_t)255; };
  char* p = (char*)d_ws;
  int* counts = (int*)p;   p += align256((size_t)N * 4);
  int* row_ptr = (int*)p;  p += align256((size_t)(N + 1) * 4);
  int* cursor = (int*)p;   p += align256((size_t)N * 4);
  float* dinv = (float*)p; p += align256((size_t)N * 4);
  int2* pairs = (int2*)p;  p += align256((size_t)E * 8);
  float* h = (float*)p;    p += align256((size_t)N * 64 * 4);

  float* out_mu = (float*)d_out;
  float* out_lv = out_mu + (size_t)N * 32;

  hipMemsetAsync(counts, 0, (size_t)N * 4, stream);
  count_edges<<<(E + 255) / 256, 256, 0, stream>>>(dst, counts, E);
  scan_deg<<<1, 1024, 0, stream>>>(counts, row_ptr, cursor, dinv, N);
  fill_csr<<<(E + 255) / 256, 256, 0, stream>>>(src, dst, dinv, cursor, pairs, E);

  const int blocks = 4096;  // 16384 waves grid-striding 100k rows
  agg_layer1<<<blocks, 256, 0, stream>>>(x, pairs, row_ptr, W1, b1, h, N);
  agg_layer2<<<blocks, 256, 0, stream>>>(h, pairs, row_ptr, Wmu, bmu, Wlv, blv,
                                         out_mu, out_lv, N);
}

// Round 2
// 514.622 us; speedup vs baseline: 1.9403x; 1.9403x over previous
//
#include <hip/hip_runtime.h>

// GCN VGAE encoder:
//   h  = relu((A @ x) @ W1 + b1)          [associativity: A(xW) == (Ax)W]
//   mu = (A @ h) @ Wmu + bmu ; lv = (A @ h) @ Wlv + blv
// A = D^-1/2 (Adj + I) D^-1/2 with deg on dst side.
// Pipeline: count -> 3-pass parallel scan -> fill CSR -> 2 pull-mode
// aggregations with fused 64-wide dense epilogue.
// Agg layout: one wave per row; 4 edges in flight (16 lanes/edge, float4 per
// lane) -> zero shfls in hot loop, 4x fewer VMEM instructions than scalar.

__global__ __launch_bounds__(256) void count_edges(const int* __restrict__ dst,
                                                   int* __restrict__ counts, int E) {
  int e = blockIdx.x * blockDim.x + threadIdx.x;
  if (e < E) atomicAdd(&counts[dst[e]], 1);
}

// Pass 1: per-block sums of counts (1024 elements/block).
__global__ __launch_bounds__(1024) void block_sums(const int* __restrict__ counts,
                                                   int* __restrict__ bsum, int n) {
  __shared__ int s[1024];
  int t = threadIdx.x;
  int i = blockIdx.x * 1024 + t;
  s[t] = (i < n) ? counts[i] : 0;
  __syncthreads();
  for (int off = 512; off > 0; off >>= 1) {
    if (t < off) s[t] += s[t + off];
    __syncthreads();
  }
  if (t == 0) bsum[blockIdx.x] = s[0];
}

// Pass 2: single-block exclusive scan over nb (<=1024) block sums, in place.
__global__ __launch_bounds__(1024) void scan_bsums(int* __restrict__ bsum, int nb) {
  __shared__ int s[1024];
  int t = threadIdx.x;
  int v = (t < nb) ? bsum[t] : 0;
  s[t] = v;
  __syncthreads();
  for (int off = 1; off < 1024; off <<= 1) {
    int u = (t >= off) ? s[t - off] : 0;
    __syncthreads();
    s[t] += u;
    __syncthreads();
  }
  if (t < nb) bsum[t] = s[t] - v;  // exclusive
}

// Pass 3: in-block inclusive scan + block offset -> row_ptr/cursor/dinv.
__global__ __launch_bounds__(1024) void scan_final(const int* __restrict__ counts,
                                                   const int* __restrict__ bofs,
                                                   int* __restrict__ row_ptr,
                                                   int* __restrict__ cursor,
                                                   float* __restrict__ dinv,
                                                   int n, int E) {
  __shared__ int s[1024];
  int t = threadIdx.x;
  int i = blockIdx.x * 1024 + t;
  int c = (i < n) ? counts[i] : 0;
  s[t] = c;
  __syncthreads();
  for (int off = 1; off < 1024; off <<= 1) {
    int u = (t >= off) ? s[t - off] : 0;
    __syncthreads();
    s[t] += u;
    __syncthreads();
  }
  if (i < n) {
    int excl = bofs[blockIdx.x] + s[t] - c;
    row_ptr[i] = excl;
    cursor[i] = excl;
    dinv[i] = rsqrtf(1.0f + (float)c);  // deg includes self-loop
  }
  if (i == 0) row_ptr[n] = E;
}

__global__ __launch_bounds__(256) void fill_csr(const int* __restrict__ src,
                                                const int* __restrict__ dst,
                                                const float* __restrict__ dinv,
                                                int* __restrict__ cursor,
                                                int2* __restrict__ pairs, int E) {
  int e = blockIdx.x * blockDim.x + threadIdx.x;
  if (e < E) {
    int s = src[e];
    int d = dst[e];
    int pos = atomicAdd(&cursor[d], 1);
    pairs[pos] = make_int2(s, __float_as_int(dinv[s]));
  }
}

// Layer 1: y = A @ x (pull), h = relu(y @ W1 + b1). One wave per row.
// lane = 16*g + q: group g handles edge slot g (4 edges/iter), lane loads
// float4 covering features q*4 .. q*4+3.
__global__ __launch_bounds__(256) void agg_layer1(const float* __restrict__ x,
                                                  const int2* __restrict__ pairs,
                                                  const int* __restrict__ row_ptr,
                                                  const float* __restrict__ W1,
                                                  const float* __restrict__ b1,
                                                  float* __restrict__ h, int n) {
  const int lane = threadIdx.x & 63;
  const int g = lane >> 4;   // edge slot 0..3
  const int q = lane & 15;   // feature quad
  float w[64];
#pragma unroll
  for (int k = 0; k < 64; ++k) w[k] = W1[k * 64 + lane];  // column `lane`
  const float bias = b1[lane];

  int wid = blockIdx.x * (blockDim.x >> 6) + (threadIdx.x >> 6);
  int nw = gridDim.x * (blockDim.x >> 6);
  for (int i = wid; i < n; i += nw) {
    int start = row_ptr[i];
    int end = row_ptr[i + 1];
    float ax = 0.f, ay = 0.f, az = 0.f, aw = 0.f;
    for (int base = start; base < end; base += 4) {
      int2 p = make_int2(i, 0);  // tail: ws = 0, safe index
      if (base + g < end) p = pairs[base + g];
      const float4 v = *(const float4*)(x + (size_t)p.x * 64 + q * 4);
      const float ws = __int_as_float(p.y);
      ax += ws * v.x; ay += ws * v.y; az += ws * v.z; aw += ws * v.w;
    }
    // reduce the 4 edge-groups: butterfly over lane^16, lane^32
#pragma unroll
    for (int off = 16; off <= 32; off <<= 1) {
      ax += __shfl_xor(ax, off); ay += __shfl_xor(ay, off);
      az += __shfl_xor(az, off); aw += __shfl_xor(aw, off);
    }
    const float di = rsqrtf((float)(1 + end - start));
    const float dii = di * di;
    const float4 xi = *(const float4*)(x + (size_t)i * 64 + q * 4);
    float y0 = di * ax + dii * xi.x;
    float y1 = di * ay + dii * xi.y;
    float y2 = di * az + dii * xi.z;
    float y3 = di * aw + dii * xi.w;
    // dense epilogue: out[lane] = b1[lane] + sum_k y[k] * W1[k][lane]
    // y[k] with k = 4*kq + c lives (identically in all groups) in lane kq.
    float out = bias;
#pragma unroll
    for (int kq = 0; kq < 16; ++kq) {
      out += __shfl(y0, kq) * w[4 * kq + 0];
      out += __shfl(y1, kq) * w[4 * kq + 1];
      out += __shfl(y2, kq) * w[4 * kq + 2];
      out += __shfl(y3, kq) * w[4 * kq + 3];
    }
    h[(size_t)i * 64 + lane] = fmaxf(out, 0.f);
  }
}

// Layer 2: y = A @ h; mu = y@Wmu + bmu (lanes 0-31), lv = y@Wlv + blv (32-63).
__global__ __launch_bounds__(256) void agg_layer2(const float* __restrict__ hin,
                                                  const int2* __restrict__ pairs,
                                                  const int* __restrict__ row_ptr,
                                                  const float* __restrict__ Wmu,
                                                  const float* __restrict__ bmu,
                                                  const float* __restrict__ Wlv,
                                                  const float* __restrict__ blv,
                                                  float* __restrict__ out_mu,
                                                  float* __restrict__ out_lv, int n) {
  const int lane = threadIdx.x & 63;
  const int g = lane >> 4;
  const int q = lane & 15;
  const int col = lane & 31;
  const float* Wsel = (lane < 32) ? Wmu : Wlv;
  float w[64];
#pragma unroll
  for (int k = 0; k < 64; ++k) w[k] = Wsel[k * 32 + col];
  const float bias = (lane < 32) ? bmu[col] : blv[col];

  int wid = blockIdx.x * (blockDim.x >> 6) + (threadIdx.x >> 6);
  int nw = gridDim.x * (blockDim.x >> 6);
  for (int i = wid; i < n; i += nw) {
    int start = row_ptr[i];
    int end = row_ptr[i + 1];
    float ax = 0.f, ay = 0.f, az = 0.f, aw = 0.f;
    for (int base = start; base < end; base += 4) {
      int2 p = make_int2(i, 0);
      if (base + g < end) p = pairs[base + g];
      const float4 v = *(const float4*)(hin + (size_t)p.x * 64 + q * 4);
      const float ws = __int_as_float(p.y);
      ax += ws * v.x; ay += ws * v.y; az += ws * v.z; aw += ws * v.w;
    }
#pragma unroll
    for (int off = 16; off <= 32; off <<= 1) {
      ax += __shfl_xor(ax, off); ay += __shfl_xor(ay, off);
      az += __shfl_xor(az, off); aw += __shfl_xor(aw, off);
    }
    const float di = rsqrtf((float)(1 + end - start));
    const float dii = di * di;
    const float4 xi = *(const float4*)(hin + (size_t)i * 64 + q * 4);
    float y0 = di * ax + dii * xi.x;
    float y1 = di * ay + dii * xi.y;
    float y2 = di * az + dii * xi.z;
    float y3 = di * aw + dii * xi.w;
    float out = bias;
#pragma unroll
    for (int kq = 0; kq < 16; ++kq) {
      out += __shfl(y0, kq) * w[4 * kq + 0];
      out += __shfl(y1, kq) * w[4 * kq + 1];
      out += __shfl(y2, kq) * w[4 * kq + 2];
      out += __shfl(y3, kq) * w[4 * kq + 3];
    }
    if (lane < 32)
      out_mu[(size_t)i * 32 + col] = out;
    else
      out_lv[(size_t)i * 32 + col] = out;
  }
}

extern "C" void kernel_launch(void* const* d_in, const int* in_sizes, int n_in,
                              void* d_out, int out_size, void* d_ws, size_t ws_size,
                              hipStream_t stream) {
  const float* x = (const float*)d_in[0];
  const int* ei = (const int*)d_in[1];  // [2, E] row-major int32
  const float* W1 = (const float*)d_in[2];
  const float* b1 = (const float*)d_in[3];
  const float* Wmu = (const float*)d_in[4];
  const float* bmu = (const float*)d_in[5];
  const float* Wlv = (const float*)d_in[6];
  const float* blv = (const float*)d_in[7];

  const int N = in_sizes[0] / 64;
  const int E = in_sizes[1] / 2;
  const int* src = ei;
  const int* dst = ei + E;

  auto align256 = [](size_t v) { return (v + 255) & ~(size_t)255; };
  char* p = (char*)d_ws;
  int* counts = (int*)p;   p += align256((size_t)N * 4);
  int* row_ptr = (int*)p;  p += align256((size_t)(N + 1) * 4);
  int* cursor = (int*)p;   p += align256((size_t)N * 4);
  float* dinv = (float*)p; p += align256((size_t)N * 4);
  int* bsum = (int*)p;     p += align256((size_t)1024 * 4);
  int2* pairs = (int2*)p;  p += align256((size_t)E * 8);
  float* h = (float*)p;    p += align256((size_t)N * 64 * 4);

  float* out_mu = (float*)d_out;
  float* out_lv = out_mu + (size_t)N * 32;

  const int NB = (N + 1023) / 1024;  // 98 for N=100k (must be <= 1024)

  hipMemsetAsync(counts, 0, (size_t)N * 4, stream);
  count_edges<<<(E + 255) / 256, 256, 0, stream>>>(dst, counts, E);
  block_sums<<<NB, 1024, 0, stream>>>(counts, bsum, N);
  scan_bsums<<<1, 1024, 0, stream>>>(bsum, NB);
  scan_final<<<NB, 1024, 0, stream>>>(counts, bsum, row_ptr, cursor, dinv, N, E);
  fill_csr<<<(E + 255) / 256, 256, 0, stream>>>(src, dst, dinv, cursor, pairs, E);

  const int blocks = 4096;  // 16384 waves grid-striding 100k rows
  agg_layer1<<<blocks, 256, 0, stream>>>(x, pairs, row_ptr, W1, b1, h, N);
  agg_layer2<<<blocks, 256, 0, stream>>>(h, pairs, row_ptr, Wmu, bmu, Wlv, blv,
                                         out_mu, out_lv, N);
}